// Round 17
// baseline (103.638 us; speedup 1.0000x reference)
//
#include <hip/hip_runtime.h>
#include <hip/hip_bf16.h>

#define CIN 128
#define COUT 256
#define H 56
#define W 56
#define OH 54
#define OW 54

typedef __attribute__((ext_vector_type(8))) short short8;
typedef __attribute__((ext_vector_type(4))) float floatx4;

typedef __attribute__((address_space(3))) unsigned int  lds_u32;
typedef const __attribute__((address_space(1))) unsigned int glb_u32;

static __device__ __forceinline__ unsigned short f2bf(float f) {
  unsigned int u = __builtin_bit_cast(unsigned int, f);
  u += 0x7fffu + ((u >> 16) & 1u);   // RNE
  return (unsigned short)(u >> 16);
}

// ---------- prepass 1: w[co][ci][kh][kw] f32 -> w2[k16][co][8] bf16 ----------
__global__ void repack_w(const float* __restrict__ w, unsigned short* __restrict__ w2) {
  int idx = blockIdx.x * 256 + threadIdx.x;
  if (idx >= COUT * CIN * 9) return;
  int kw = idx % 3, t1 = idx / 3;
  int kh = t1 % 3, t2 = t1 / 3;
  int ci = t2 % CIN;
  int co = t2 / CIN;
  int c8 = ci >> 3, j = ci & 7;
  w2[((((kh * 3 + kw) * 16 + c8) * COUT + co) * 8) + j] = f2bf(w[idx]);
}

// ---------- prepass 2 (LDS transpose, coalesced both sides) ----------
// x NCHW f32 -> xb[n][h][g'] bf16, g' = iw*16 + (c16 ^ (iw&7)).
__global__ __launch_bounds__(256) void repack_x(const float* __restrict__ x,
                                                unsigned short* __restrict__ xb) {
  __shared__ float xt[56][129];
  const int h = blockIdx.x;       // 0..55
  const int n = blockIdx.y;       // 0..31
  const float* src = x + (size_t)n * CIN * (H * W) + h * W;
  #pragma unroll
  for (int r = 0; r < 28; ++r) {
    int idx = r * 256 + threadIdx.x;
    int ci = idx / 56, iw = idx % 56;
    xt[iw][ci] = src[ci * (H * W) + iw];
  }
  __syncthreads();
  unsigned short* dst = xb + ((size_t)n * H + h) * 896 * 8;
  #pragma unroll
  for (int r = 0; r < 4; ++r) {
    int g = r * 256 + threadIdx.x;
    if (g < 896) {
      int iw = g >> 4, c16 = g & 15;
      short8 v;
      #pragma unroll
      for (int j = 0; j < 8; ++j)
        v[j] = (short)f2bf(xt[iw][c16 * 8 + j]);
      int gp = iw * 16 + (c16 ^ (iw & 7));
      *reinterpret_cast<short8*>(&dst[gp * 8]) = v;
    }
  }
}

// ---------- main conv: 4-row blocks (halved A-stream) ----------
// 512 threads = 8 waves = 4 co-groups x 2 row-pairs; block = 4 rows x 256 co.
// Per-CU A(L2) traffic halves vs 2-row blocks (each block streams all of w2);
// staging drops 22% (6 in-rows per 4 out-rows). Trim (7 frags / 108 px) and
// opaque asm-A depth-1 pipeline kept; LDS 87 KB -> 1 block/CU, 2 waves/SIMD.
__global__ __launch_bounds__(512, 2) void conv10(
    const unsigned short* __restrict__ xb, const unsigned short* __restrict__ w2,
    const float* __restrict__ bias, float* __restrict__ out) {
  __shared__ alignas(16) unsigned short xs[5440 * 8];   // 6 rows + overrun pad = 87,040 B

  // XCD-bijective swizzle: 448 % 8 == 0
  const int f = blockIdx.x;
  const int swz = (f & 7) * 56 + (f >> 3);
  const int ohq = swz % 14;        // 0..13, oh0 = 4*ohq (tail quad masked)
  const int n   = swz / 14;
  const int oh0 = ohq * 4;
  const int tid = threadIdx.x;
  const int wid  = tid >> 6;       // 0..7
  const int lane = tid & 63;

  // ---- stage rows oh0..oh0+5 (5376 granules = 84 chunks), 10-11 issues/wave ----
  // Tail quad: source row clamped to 55 (dup row); consumers masked.
  {
    #pragma unroll
    for (int i = 0; i < 11; ++i) {
      int c = i * 8 + wid;
      if (c < 84) {
        int row = c / 14, part = c % 14;
        int srow = oh0 + row; if (srow > 55) srow = 55;
        const unsigned short* src =
            xb + (((size_t)n * H + srow) * 896 + part * 64 + lane) * 8;
        __builtin_amdgcn_global_load_lds(
            (glb_u32*)src, (lds_u32*)(&xs[(size_t)c * 64 * 8]), 16, 0, 0);
      }
    }
  }

  const int wm   = wid & 3;        // co group (0..3)
  const int wn   = wid >> 2;       // row pair (0/1)
  const int l16  = lane & 15;
  const int cig  = lane >> 4;      // 0..3
  const int co_base = wm * 64;
  const int rowd = cig * 4;
  const int rbase = 2 * wn;        // slab row base for this wave's pair

  // per-lane pixel tables: frag fr covers p = fr*16 + l16 (0..111) of the pair
  int rp[7], owp[7];
  #pragma unroll
  for (int fr = 0; fr < 7; ++fr) {
    int p = fr * 16 + l16;
    rp[fr]  = (p < 54) ? 0 : 1;
    owp[fr] = p - rp[fr] * 54;     // 54..57 for pad lanes -> in-slab garbage
  }

  short8 areg[2][4];   // depth-1 opaque rotation (32 VGPRs)

#define AISSUE(s, slot)                                                          \
  {                                                                              \
    const int kh_ = (s) / 12, ch_ = ((s) / 3) & 3, kw_ = (s) % 3;                \
    const unsigned short* wp_ =                                                  \
        w2 + ((size_t)(((kh_ * 3 + kw_) * 16 + (ch_ * 4 + cig)) * COUT + co_base + l16)) * 8; \
    asm volatile("global_load_dwordx4 %0, %1, off"            : "=v"(areg[slot][0]) : "v"(wp_)); \
    asm volatile("global_load_dwordx4 %0, %1, off offset:256" : "=v"(areg[slot][1]) : "v"(wp_)); \
    asm volatile("global_load_dwordx4 %0, %1, off offset:512" : "=v"(areg[slot][2]) : "v"(wp_)); \
    asm volatile("global_load_dwordx4 %0, %1, off offset:768" : "=v"(areg[slot][3]) : "v"(wp_)); \
  }

  AISSUE(0, 0);
  // drain staging + A(0) together; one barrier for xs visibility
  asm volatile("s_waitcnt vmcnt(0)" ::: "memory");
  __syncthreads();

  floatx4 acc[4][7];
  #pragma unroll
  for (int m = 0; m < 4; ++m)
    #pragma unroll
    for (int fr = 0; fr < 7; ++fr)
      acc[m][fr] = (floatx4){0.f, 0.f, 0.f, 0.f};

  #pragma unroll
  for (int s = 0; s < 36; ++s) {
    if (s < 35) AISSUE(s + 1, (s + 1) & 1);   // one step in flight

    const int kh = s / 12, ch = (s / 3) & 3, kw = s % 3;
    const int chb = ch * 4 + cig;
    short8 b[7];
    #pragma unroll
    for (int fr = 0; fr < 7; ++fr) {
      const int iwl = owp[fr] + kw;
      const int c16x = chb ^ (iwl & 7);
      const int boff = ((rbase + rp[fr] + kh) * 896 + iwl * 16 + c16x) * 8;
      b[fr] = *reinterpret_cast<const short8*>(&xs[boff]);
    }

    // counted wait: A(s) landed; A(s+1) stays in flight
    if (s < 35) asm volatile("s_waitcnt vmcnt(4)" ::: "memory");
    else        asm volatile("s_waitcnt vmcnt(0)" ::: "memory");
    __builtin_amdgcn_sched_barrier(0);   // MFMA may not hoist above the wait

    __builtin_amdgcn_s_setprio(1);
    #pragma unroll
    for (int m = 0; m < 4; ++m)
      #pragma unroll
      for (int fr = 0; fr < 7; ++fr)
        acc[m][fr] = __builtin_amdgcn_mfma_f32_16x16x32_bf16(
            areg[s & 1][m], b[fr], acc[m][fr], 0, 0, 0);
    __builtin_amdgcn_s_setprio(0);
  }
#undef AISSUE

  // ---- epilogue: C/D col=lane&15 (pixel), row=(lane>>4)*4+reg (co) ----
  #pragma unroll
  for (int m = 0; m < 4; ++m) {
    #pragma unroll
    for (int reg = 0; reg < 4; ++reg) {
      int co = co_base + m * 16 + rowd + reg;
      float bvv = bias[co];
      #pragma unroll
      for (int fr = 0; fr < 7; ++fr) {
        int p = fr * 16 + l16;
        int oh = oh0 + rbase + rp[fr];
        if (p < 108 && oh < OH)
          out[((((size_t)n * COUT + co) * OH + oh) * OW) + owp[fr]] =
              acc[m][fr][reg] + bvv;
      }
    }
  }
}

// ================== fallback path (ws too small): round-2 kernel ==================
#define CSTR 136
#define IWP 66

__global__ void repack_w_fb(const float* __restrict__ w, unsigned short* __restrict__ w2) {
  int idx = blockIdx.x * 256 + threadIdx.x;
  if (idx >= COUT * CIN * 9) return;
  int kw = idx % 3, t1 = idx / 3;
  int kh = t1 % 3, t2 = t1 / 3;
  int ci = t2 % CIN;
  int co = t2 / CIN;
  int c8 = ci >> 3, j = ci & 7;
  w2[((((kh * 3 + kw) * 16 + c8) * COUT + co) * 8) + j] = f2bf(w[idx]);
}

__global__ __launch_bounds__(512, 4) void conv_fb(
    const float* __restrict__ x, const unsigned short* __restrict__ w2,
    const float* __restrict__ bias, float* __restrict__ out) {
  __shared__ alignas(16) unsigned short xsf[4 * IWP * CSTR];

  const int ohp = blockIdx.x;
  const int n   = blockIdx.y;
  const int oh0 = ohp * 2;
  const int tid = threadIdx.x;

  {
    short8 zz = {0, 0, 0, 0, 0, 0, 0, 0};
    for (int i = tid; i < 4 * 10 * 17; i += 512) {
      int r = i / 170, rem = i % 170;
      int iw = 56 + rem / 17, g = rem % 17;
      *reinterpret_cast<short8*>(&xsf[(r * IWP + iw) * CSTR + g * 8]) = zz;
    }
  }
  for (int s = tid; s < 3584; s += 512) {
    int iw = s % 56;
    int t  = s / 56;
    int c8 = t & 15, r = t >> 4;
    const float* xp = x + (size_t)n * CIN * (H * W) + (oh0 + r) * W + iw;
    short8 v;
    #pragma unroll
    for (int j = 0; j < 8; ++j)
      v[j] = (short)f2bf(xp[(size_t)(c8 * 8 + j) * (H * W)]);
    *reinterpret_cast<short8*>(&xsf[(r * IWP + iw) * CSTR + c8 * 8]) = v;
  }
  __syncthreads();

  const int wid  = tid >> 6;
  const int lane = tid & 63;
  const int wm   = wid >> 1;
  const int wn   = wid & 1;
  const int l16  = lane & 15;
  const int cig  = lane >> 4;

  const int co_base = wm * 64;
  const int oh = oh0 + wn;

  floatx4 acc[4][4];
  #pragma unroll
  for (int m = 0; m < 4; ++m)
    #pragma unroll
    for (int nr = 0; nr < 4; ++nr)
      acc[m][nr] = (floatx4){0.f, 0.f, 0.f, 0.f};

  for (int kh = 0; kh < 3; ++kh) {
    const int row = wn + kh;
    #pragma unroll
    for (int ch = 0; ch < 4; ++ch) {
      const int bbase = (row * IWP + l16) * CSTR + ch * 32 + cig * 8;
      #pragma unroll
      for (int kw = 0; kw < 3; ++kw) {
        const unsigned short* wp =
            w2 + ((size_t)(((kh * 3 + kw) * 16 + (ch * 4 + cig)) * COUT + co_base + l16)) * 8;
        short8 a[4];
        #pragma unroll
        for (int m = 0; m < 4; ++m)
          a[m] = *reinterpret_cast<const short8*>(wp + m * 16 * 8);
        short8 b[4];
        #pragma unroll
        for (int nr = 0; nr < 4; ++nr)
          b[nr] = *reinterpret_cast<const short8*>(&xsf[bbase + (nr * 16 + kw) * CSTR]);
        #pragma unroll
        for (int m = 0; m < 4; ++m)
          #pragma unroll
          for (int nr = 0; nr < 4; ++nr)
            acc[m][nr] = __builtin_amdgcn_mfma_f32_16x16x32_bf16(a[m], b[nr], acc[m][nr], 0, 0, 0);
      }
    }
  }

  const int rowd = cig * 4;
  #pragma unroll
  for (int m = 0; m < 4; ++m) {
    #pragma unroll
    for (int reg = 0; reg < 4; ++reg) {
      int co = co_base + m * 16 + rowd + reg;
      float bvv = bias[co];
      float* op = out + (((size_t)n * COUT + co) * OH + oh) * OW;
      #pragma unroll
      for (int nr = 0; nr < 4; ++nr) {
        int ow = nr * 16 + l16;
        if (ow < OW) op[ow] = acc[m][nr][reg] + bvv;
      }
    }
  }
}

extern "C" void kernel_launch(void* const* d_in, const int* in_sizes, int n_in,
                              void* d_out, int out_size, void* d_ws, size_t ws_size,
                              hipStream_t stream) {
  (void)in_sizes; (void)n_in; (void)out_size;
  const float* x    = (const float*)d_in[0];
  const float* w    = (const float*)d_in[1];
  const float* bias = (const float*)d_in[2];
  float* out = (float*)d_out;

  const size_t W2_BYTES = (size_t)9 * 16 * COUT * 8 * 2;            // 589,824
  const size_t XB_BYTES = (size_t)32 * H * 896 * 8 * 2;             // 25,690,112
  unsigned short* w2 = (unsigned short*)d_ws;

  repack_w<<<dim3((COUT * CIN * 9 + 255) / 256), dim3(256), 0, stream>>>(w, w2);

  if (ws_size >= W2_BYTES + XB_BYTES) {
    unsigned short* xb = (unsigned short*)((char*)d_ws + W2_BYTES);
    repack_x<<<dim3(56, 32), dim3(256), 0, stream>>>(x, xb);
    conv10<<<dim3(448), dim3(512), 0, stream>>>(xb, w2, bias, out);
  } else {
    conv_fb<<<dim3(27, 32), dim3(512), 0, stream>>>(x, w2, bias, out);
  }
}

// Round 18
// 78.776 us; speedup vs baseline: 1.3156x; 1.3156x over previous
//
#include <hip/hip_runtime.h>
#include <hip/hip_bf16.h>

#define CIN 128
#define COUT 256
#define H 56
#define W 56
#define OH 54
#define OW 54

typedef __attribute__((ext_vector_type(8))) short short8;
typedef __attribute__((ext_vector_type(4))) float floatx4;

typedef __attribute__((address_space(3))) unsigned int  lds_u32;
typedef const __attribute__((address_space(1))) unsigned int glb_u32;

static __device__ __forceinline__ unsigned short f2bf(float f) {
  unsigned int u = __builtin_bit_cast(unsigned int, f);
  u += 0x7fffu + ((u >> 16) & 1u);   // RNE
  return (unsigned short)(u >> 16);
}

// ---------- fused prepass ----------
// blocks [0,1792): x NCHW f32 -> xb[n][h][g'] bf16, g' = iw*16 + (c16^(iw&7))
// blocks [1792,1828): w[co][ci][kh][kw] f32 -> w2[k16][co][8] bf16 (32 elems/thr)
__global__ __launch_bounds__(256) void prepack(const float* __restrict__ x,
                                               unsigned short* __restrict__ xb,
                                               const float* __restrict__ w,
                                               unsigned short* __restrict__ w2) {
  if (blockIdx.x >= 1792) {
    const int wb = blockIdx.x - 1792;            // 0..35
    int base = wb * 8192 + threadIdx.x;
    #pragma unroll
    for (int k2 = 0; k2 < 32; ++k2) {
      int idx = base + k2 * 256;                 // < 294912 always
      int kw = idx % 3, t1 = idx / 3;
      int kh = t1 % 3, t2 = t1 / 3;
      int ci = t2 % CIN;
      int co = t2 / CIN;
      int c8 = ci >> 3, j = ci & 7;
      w2[((((kh * 3 + kw) * 16 + c8) * COUT + co) * 8) + j] = f2bf(w[idx]);
    }
    return;
  }
  __shared__ float xt[56][129];
  const int h = blockIdx.x % 56;
  const int n = blockIdx.x / 56;
  const float* src = x + (size_t)n * CIN * (H * W) + h * W;
  #pragma unroll
  for (int r = 0; r < 28; ++r) {
    int idx = r * 256 + threadIdx.x;
    int ci = idx / 56, iw = idx % 56;
    xt[iw][ci] = src[ci * (H * W) + iw];
  }
  __syncthreads();
  unsigned short* dst = xb + ((size_t)n * H + h) * 896 * 8;
  #pragma unroll
  for (int r = 0; r < 4; ++r) {
    int g = r * 256 + threadIdx.x;
    if (g < 896) {
      int iw = g >> 4, c16 = g & 15;
      short8 v;
      #pragma unroll
      for (int j = 0; j < 8; ++j)
        v[j] = (short)f2bf(xt[iw][c16 * 8 + j]);
      int gp = iw * 16 + (c16 ^ (iw & 7));
      *reinterpret_cast<short8*>(&dst[gp * 8]) = v;
    }
  }
}

// ---------- main conv: conv9 structure, depth-1 opaque A pipeline (no spill) ----------
// 256 thr = 4 waves = 4 co-groups; block = 2 rows x 256 co; 7 px-frags (3.6% pad).
// asm global_load_dwordx4 A-prefetch 1 step ahead, counted vmcnt(4);
// sched_barrier(0) stops MFMA hoisting (rule #18). 2 blocks/CU.
__global__ __launch_bounds__(256, 2) void conv11(
    const unsigned short* __restrict__ xb, const unsigned short* __restrict__ w2,
    const float* __restrict__ bias, float* __restrict__ out) {
  __shared__ alignas(16) unsigned short xs[3744 * 8];   // 4 rows + overrun pad = 59,904 B

  // XCD-bijective swizzle: 864 % 8 == 0
  const int f = blockIdx.x;
  const int swz = (f & 7) * 108 + (f >> 3);
  const int ohp = swz % 27;
  const int n   = swz / 27;
  const int oh0 = ohp * 2;
  const int tid = threadIdx.x;
  const int wid  = tid >> 6;       // co group (0..3)
  const int lane = tid & 63;

  // ---- stage rows oh0..oh0+3 (3584 granules), 14 issues/wave ----
  {
    const unsigned short* src = xb + ((size_t)n * H + oh0) * 896 * 8;
    #pragma unroll
    for (int i = 0; i < 14; ++i) {
      int idx = (wid * 14 + i) * 64;
      __builtin_amdgcn_global_load_lds(
          (glb_u32*)(src + (size_t)(idx + lane) * 8),
          (lds_u32*)(&xs[idx * 8]), 16, 0, 0);
    }
  }
  asm volatile("s_waitcnt vmcnt(0)" ::: "memory");
  __syncthreads();

  const int l16  = lane & 15;
  const int cig  = lane >> 4;      // 0..3
  const int co_base = wid * 64;
  const int rowd = cig * 4;

  // per-lane pixel tables: frag fr covers p = fr*16 + l16 (0..111)
  int rp[7], owp[7];
  #pragma unroll
  for (int fr = 0; fr < 7; ++fr) {
    int p = fr * 16 + l16;
    rp[fr]  = (p < 54) ? 0 : 1;
    owp[fr] = p - rp[fr] * 54;
  }

  floatx4 acc[4][7];
  #pragma unroll
  for (int m = 0; m < 4; ++m)
    #pragma unroll
    for (int fr = 0; fr < 7; ++fr)
      acc[m][fr] = (floatx4){0.f, 0.f, 0.f, 0.f};

  short8 areg[2][4];   // depth-1 rotation: 32 VGPRs (spill-free budget)

#define AISSUE(s, slot)                                                          \
  {                                                                              \
    const int kh_ = (s) / 12, ch_ = ((s) / 3) & 3, kw_ = (s) % 3;                \
    const unsigned short* wp_ =                                                  \
        w2 + ((size_t)(((kh_ * 3 + kw_) * 16 + (ch_ * 4 + cig)) * COUT + co_base + l16)) * 8; \
    asm volatile("global_load_dwordx4 %0, %1, off"            : "=v"(areg[slot][0]) : "v"(wp_)); \
    asm volatile("global_load_dwordx4 %0, %1, off offset:256" : "=v"(areg[slot][1]) : "v"(wp_)); \
    asm volatile("global_load_dwordx4 %0, %1, off offset:512" : "=v"(areg[slot][2]) : "v"(wp_)); \
    asm volatile("global_load_dwordx4 %0, %1, off offset:768" : "=v"(areg[slot][3]) : "v"(wp_)); \
  }

  AISSUE(0, 0);

  #pragma unroll
  for (int s = 0; s < 36; ++s) {
    if (s < 35) AISSUE(s + 1, (s + 1) & 1);   // one step in flight

    // B fragments (LDS) — issue before the vm wait
    const int kh = s / 12, ch = (s / 3) & 3, kw = s % 3;
    const int chb = ch * 4 + cig;
    short8 b[7];
    #pragma unroll
    for (int fr = 0; fr < 7; ++fr) {
      const int iwl = owp[fr] + kw;
      const int c16x = chb ^ (iwl & 7);
      const int boff = ((rp[fr] + kh) * 896 + iwl * 16 + c16x) * 8;
      b[fr] = *reinterpret_cast<const short8*>(&xs[boff]);
    }

    // counted wait: A(s) landed; A(s+1) stays in flight
    if (s < 35) asm volatile("s_waitcnt vmcnt(4)" ::: "memory");
    else        asm volatile("s_waitcnt vmcnt(0)" ::: "memory");
    __builtin_amdgcn_sched_barrier(0);

    __builtin_amdgcn_s_setprio(1);
    #pragma unroll
    for (int m = 0; m < 4; ++m)
      #pragma unroll
      for (int fr = 0; fr < 7; ++fr)
        acc[m][fr] = __builtin_amdgcn_mfma_f32_16x16x32_bf16(
            areg[s & 1][m], b[fr], acc[m][fr], 0, 0, 0);
    __builtin_amdgcn_s_setprio(0);
  }
#undef AISSUE

  // ---- epilogue: C/D col=lane&15 (pixel), row=(lane>>4)*4+reg (co) ----
  #pragma unroll
  for (int m = 0; m < 4; ++m) {
    #pragma unroll
    for (int reg = 0; reg < 4; ++reg) {
      int co = co_base + m * 16 + rowd + reg;
      float bvv = bias[co];
      float* opb = out + (((size_t)n * COUT + co) * OH + oh0) * OW;
      #pragma unroll
      for (int fr = 0; fr < 7; ++fr) {
        int p = fr * 16 + l16;
        if (p < 108)
          opb[rp[fr] * OW + owp[fr]] = acc[m][fr][reg] + bvv;
      }
    }
  }
}

// ================== fallback path (ws too small): round-2 kernel ==================
#define CSTR 136
#define IWP 66

__global__ void repack_w_fb(const float* __restrict__ w, unsigned short* __restrict__ w2) {
  int idx = blockIdx.x * 256 + threadIdx.x;
  if (idx >= COUT * CIN * 9) return;
  int kw = idx % 3, t1 = idx / 3;
  int kh = t1 % 3, t2 = t1 / 3;
  int ci = t2 % CIN;
  int co = t2 / CIN;
  int c8 = ci >> 3, j = ci & 7;
  w2[((((kh * 3 + kw) * 16 + c8) * COUT + co) * 8) + j] = f2bf(w[idx]);
}

__global__ __launch_bounds__(512, 4) void conv_fb(
    const float* __restrict__ x, const unsigned short* __restrict__ w2,
    const float* __restrict__ bias, float* __restrict__ out) {
  __shared__ alignas(16) unsigned short xsf[4 * IWP * CSTR];

  const int ohp = blockIdx.x;
  const int n   = blockIdx.y;
  const int oh0 = ohp * 2;
  const int tid = threadIdx.x;

  {
    short8 zz = {0, 0, 0, 0, 0, 0, 0, 0};
    for (int i = tid; i < 4 * 10 * 17; i += 512) {
      int r = i / 170, rem = i % 170;
      int iw = 56 + rem / 17, g = rem % 17;
      *reinterpret_cast<short8*>(&xsf[(r * IWP + iw) * CSTR + g * 8]) = zz;
    }
  }
  for (int s = tid; s < 3584; s += 512) {
    int iw = s % 56;
    int t  = s / 56;
    int c8 = t & 15, r = t >> 4;
    const float* xp = x + (size_t)n * CIN * (H * W) + (oh0 + r) * W + iw;
    short8 v;
    #pragma unroll
    for (int j = 0; j < 8; ++j)
      v[j] = (short)f2bf(xp[(size_t)(c8 * 8 + j) * (H * W)]);
    *reinterpret_cast<short8*>(&xsf[(r * IWP + iw) * CSTR + c8 * 8]) = v;
  }
  __syncthreads();

  const int wid  = tid >> 6;
  const int lane = tid & 63;
  const int wm   = wid >> 1;
  const int wn   = wid & 1;
  const int l16  = lane & 15;
  const int cig  = lane >> 4;

  const int co_base = wm * 64;
  const int oh = oh0 + wn;

  floatx4 acc[4][4];
  #pragma unroll
  for (int m = 0; m < 4; ++m)
    #pragma unroll
    for (int nr = 0; nr < 4; ++nr)
      acc[m][nr] = (floatx4){0.f, 0.f, 0.f, 0.f};

  for (int kh = 0; kh < 3; ++kh) {
    const int row = wn + kh;
    #pragma unroll
    for (int ch = 0; ch < 4; ++ch) {
      const int bbase = (row * IWP + l16) * CSTR + ch * 32 + cig * 8;
      #pragma unroll
      for (int kw = 0; kw < 3; ++kw) {
        const unsigned short* wp =
            w2 + ((size_t)(((kh * 3 + kw) * 16 + (ch * 4 + cig)) * COUT + co_base + l16)) * 8;
        short8 a[4];
        #pragma unroll
        for (int m = 0; m < 4; ++m)
          a[m] = *reinterpret_cast<const short8*>(wp + m * 16 * 8);
        short8 b[4];
        #pragma unroll
        for (int nr = 0; nr < 4; ++nr)
          b[nr] = *reinterpret_cast<const short8*>(&xsf[bbase + (nr * 16 + kw) * CSTR]);
        #pragma unroll
        for (int m = 0; m < 4; ++m)
          #pragma unroll
          for (int nr = 0; nr < 4; ++nr)
            acc[m][nr] = __builtin_amdgcn_mfma_f32_16x16x32_bf16(a[m], b[nr], acc[m][nr], 0, 0, 0);
      }
    }
  }

  const int rowd = cig * 4;
  #pragma unroll
  for (int m = 0; m < 4; ++m) {
    #pragma unroll
    for (int reg = 0; reg < 4; ++reg) {
      int co = co_base + m * 16 + rowd + reg;
      float bvv = bias[co];
      float* op = out + (((size_t)n * COUT + co) * OH + oh) * OW;
      #pragma unroll
      for (int nr = 0; nr < 4; ++nr) {
        int ow = nr * 16 + l16;
        if (ow < OW) op[ow] = acc[m][nr][reg] + bvv;
      }
    }
  }
}

extern "C" void kernel_launch(void* const* d_in, const int* in_sizes, int n_in,
                              void* d_out, int out_size, void* d_ws, size_t ws_size,
                              hipStream_t stream) {
  (void)in_sizes; (void)n_in; (void)out_size;
  const float* x    = (const float*)d_in[0];
  const float* w    = (const float*)d_in[1];
  const float* bias = (const float*)d_in[2];
  float* out = (float*)d_out;

  const size_t W2_BYTES = (size_t)9 * 16 * COUT * 8 * 2;            // 589,824
  const size_t XB_BYTES = (size_t)32 * H * 896 * 8 * 2;             // 25,690,112
  unsigned short* w2 = (unsigned short*)d_ws;

  if (ws_size >= W2_BYTES + XB_BYTES) {
    unsigned short* xb = (unsigned short*)((char*)d_ws + W2_BYTES);
    prepack<<<dim3(1828), dim3(256), 0, stream>>>(x, xb, w, w2);
    conv11<<<dim3(864), dim3(256), 0, stream>>>(xb, w2, bias, out);
  } else {
    repack_w_fb<<<dim3((COUT * CIN * 9 + 255) / 256), dim3(256), 0, stream>>>(w, w2);
    conv_fb<<<dim3(27, 32), dim3(512), 0, stream>>>(x, w2, bias, out);
  }
}